// Round 1
// baseline (717.317 us; speedup 1.0000x reference)
//
#include <hip/hip_runtime.h>

typedef unsigned short u16;
typedef unsigned int u32;
typedef __attribute__((ext_vector_type(8))) short short8v;
typedef __attribute__((ext_vector_type(4))) float floatx4;

#define BB 4
#define SS 2048
#define DD 1024
#define HH 16
#define DKK 64
#define MM (BB * SS)   // 8192
#define KK DD          // 1024
#define NN DD          // 1024

__device__ __forceinline__ u16 f2bf(float f) {
  union { float f; u32 u; } v; v.f = f;
  u32 r = (v.u + 0x7fffu + ((v.u >> 16) & 1u)) >> 16;  // RNE, inputs are normal
  return (u16)r;
}

__device__ __forceinline__ void load_lds16(const void* g, void* l) {
  __builtin_amdgcn_global_load_lds((const __attribute__((address_space(1))) void*)g,
                                   (__attribute__((address_space(3))) void*)l, 16, 0, 0);
}

__device__ __forceinline__ floatx4 mfma_bf16(short8v a, short8v b, floatx4 c) {
  return __builtin_amdgcn_mfma_f32_16x16x32_bf16(a, b, c, 0, 0, 0);
}

// ---------------- fp32 -> bf16 convert (weights) ----------------
__global__ __launch_bounds__(256) void cvt_bf16(const float* __restrict__ in,
                                                u16* __restrict__ out, int n) {
  int i = (blockIdx.x * 256 + threadIdx.x) * 8;
  if (i + 8 > n) return;
  float4 a = *(const float4*)(in + i);
  float4 b = *(const float4*)(in + i + 4);
  union { u16 h[8]; short8v v; } r;
  r.h[0] = f2bf(a.x); r.h[1] = f2bf(a.y); r.h[2] = f2bf(a.z); r.h[3] = f2bf(a.w);
  r.h[4] = f2bf(b.x); r.h[5] = f2bf(b.y); r.h[6] = f2bf(b.z); r.h[7] = f2bf(b.w);
  *(short8v*)(out + i) = r.v;
}

// ---------------- projection GEMM: out = A @ W^T + bias ----------------
// A fp32 [M,K]; W bf16 [N,K]; SMODE 0: store bf16 [B,H,S,DK]; 1: store bf16 [B,H,DK,S]
// LDS fragment-order layout: chunk(blk, k-octet q, row r) -> flat = blk*64 + q*16 + r,
// so ds_read offset for frag = blk*512 + lane*8 u16 (linear, conflict-free).
template <int SMODE>
__global__ __launch_bounds__(256) void proj_gemm(const float* __restrict__ A,
                                                 const u16* __restrict__ W,
                                                 const float* __restrict__ bias,
                                                 u16* __restrict__ out) {
  __shared__ __align__(16) u16 As[64 * 32];
  __shared__ __align__(16) u16 Bs[64 * 32];
  const int tid = threadIdx.x;
  const int w = tid >> 6, lane = tid & 63;
  const int lr = lane & 15, lq = lane >> 4;
  const int m0 = blockIdx.x * 64, n0 = blockIdx.y * 64;
  const int wrow = w >> 1, wcol = w & 1;

  floatx4 acc[2][2] = {{{0.f,0.f,0.f,0.f},{0.f,0.f,0.f,0.f}},
                       {{0.f,0.f,0.f,0.f},{0.f,0.f,0.f,0.f}}};

  const float* ga = A + (size_t)(m0 + w * 16 + lr) * KK + lq * 8;
  const u16*   gb = W + (size_t)(n0 + w * 16 + lr) * KK + lq * 8;
  u16* as_dst = &As[(w * 64 + lane) * 8];
  u16* bs_base = &Bs[w * 512];  // wave-uniform; HW adds lane*16B

  for (int k0 = 0; k0 < KK; k0 += 32) {
    load_lds16(gb + k0, bs_base);
    float4 f0 = *(const float4*)(ga + k0);
    float4 f1 = *(const float4*)(ga + k0 + 4);
    union { u16 h[8]; short8v v; } hh;
    hh.h[0] = f2bf(f0.x); hh.h[1] = f2bf(f0.y); hh.h[2] = f2bf(f0.z); hh.h[3] = f2bf(f0.w);
    hh.h[4] = f2bf(f1.x); hh.h[5] = f2bf(f1.y); hh.h[6] = f2bf(f1.z); hh.h[7] = f2bf(f1.w);
    *(short8v*)as_dst = hh.v;
    __syncthreads();
    short8v af0 = *(const short8v*)&As[(wrow * 2 + 0) * 512 + lane * 8];
    short8v af1 = *(const short8v*)&As[(wrow * 2 + 1) * 512 + lane * 8];
    short8v bf0 = *(const short8v*)&Bs[(wcol * 2 + 0) * 512 + lane * 8];
    short8v bf1 = *(const short8v*)&Bs[(wcol * 2 + 1) * 512 + lane * 8];
    acc[0][0] = mfma_bf16(af0, bf0, acc[0][0]);
    acc[0][1] = mfma_bf16(af0, bf1, acc[0][1]);
    acc[1][0] = mfma_bf16(af1, bf0, acc[1][0]);
    acc[1][1] = mfma_bf16(af1, bf1, acc[1][1]);
    __syncthreads();
  }
#pragma unroll
  for (int j = 0; j < 2; ++j) {
    const int col = n0 + wcol * 32 + j * 16 + lr;
    const float bv = bias[col];
    const int h = col >> 6, dk = col & 63;
#pragma unroll
    for (int i = 0; i < 2; ++i) {
#pragma unroll
      for (int r = 0; r < 4; ++r) {
        const int row = m0 + wrow * 32 + i * 16 + lq * 4 + r;
        const int b = row >> 11, s = row & 2047;  // S = 2048
        const u16 hv = f2bf(acc[i][j][r] + bv);
        if (SMODE == 0)
          out[(((size_t)(b * HH + h)) * SS + s) * DKK + dk] = hv;
        else
          out[(((size_t)(b * HH + h)) * DKK + dk) * SS + s] = hv;
      }
    }
  }
}

// ---------------- output GEMM: out = ctx @ Wo^T + bias (fp32 store) ----------------
__global__ __launch_bounds__(256) void out_gemm(const u16* __restrict__ A,
                                                const u16* __restrict__ W,
                                                const float* __restrict__ bias,
                                                float* __restrict__ out) {
  __shared__ __align__(16) u16 As[64 * 32];
  __shared__ __align__(16) u16 Bs[64 * 32];
  const int tid = threadIdx.x;
  const int w = tid >> 6, lane = tid & 63;
  const int lr = lane & 15, lq = lane >> 4;
  const int m0 = blockIdx.x * 64, n0 = blockIdx.y * 64;
  const int wrow = w >> 1, wcol = w & 1;

  floatx4 acc[2][2] = {{{0.f,0.f,0.f,0.f},{0.f,0.f,0.f,0.f}},
                       {{0.f,0.f,0.f,0.f},{0.f,0.f,0.f,0.f}}};

  const u16* ga = A + (size_t)(m0 + w * 16 + lr) * KK + lq * 8;
  const u16* gb = W + (size_t)(n0 + w * 16 + lr) * KK + lq * 8;
  u16* as_base = &As[w * 512];
  u16* bs_base = &Bs[w * 512];

  for (int k0 = 0; k0 < KK; k0 += 32) {
    load_lds16(ga + k0, as_base);
    load_lds16(gb + k0, bs_base);
    __syncthreads();
    short8v af0 = *(const short8v*)&As[(wrow * 2 + 0) * 512 + lane * 8];
    short8v af1 = *(const short8v*)&As[(wrow * 2 + 1) * 512 + lane * 8];
    short8v bf0 = *(const short8v*)&Bs[(wcol * 2 + 0) * 512 + lane * 8];
    short8v bf1 = *(const short8v*)&Bs[(wcol * 2 + 1) * 512 + lane * 8];
    acc[0][0] = mfma_bf16(af0, bf0, acc[0][0]);
    acc[0][1] = mfma_bf16(af0, bf1, acc[0][1]);
    acc[1][0] = mfma_bf16(af1, bf0, acc[1][0]);
    acc[1][1] = mfma_bf16(af1, bf1, acc[1][1]);
    __syncthreads();
  }
#pragma unroll
  for (int j = 0; j < 2; ++j) {
    const int col = n0 + wcol * 32 + j * 16 + lr;
    const float bv = bias[col];
#pragma unroll
    for (int i = 0; i < 2; ++i) {
#pragma unroll
      for (int r = 0; r < 4; ++r) {
        const int row = m0 + wrow * 32 + i * 16 + lq * 4 + r;
        out[(size_t)row * NN + col] = acc[i][j][r] + bv;
      }
    }
  }
}

// ---------------- flash attention ----------------
// Q,K bf16 [B,H,S,DK]; Vt bf16 [B,H,DK,S]; ctx bf16 [B,S,D]
// Block: 4 waves x 16 queries = 64 queries. Each wave owns its Q strip in regs.
__global__ __launch_bounds__(256) void attn_kernel(const u16* __restrict__ Q,
                                                   const u16* __restrict__ Kmat,
                                                   const u16* __restrict__ Vt,
                                                   u16* __restrict__ ctx) {
  __shared__ __align__(16) u16 Ks[64 * 64];   // chunk(keyblk, dk-octet, key%16)
  __shared__ __align__(16) u16 Vs[64 * 64];   // chunk(dkblk, key-octet, dk%16)
  __shared__ __align__(16) u16 Ps[4 * 1024];  // per-wave P strip, A-operand order
  const int tid = threadIdx.x;
  const int w = tid >> 6, lane = tid & 63;
  const int lr = lane & 15, lq = lane >> 4;
  const int bh = blockIdx.y;
  const int q0 = blockIdx.x * 64;
  const u16* Qb = Q    + (size_t)bh * SS * DKK;
  const u16* Kb = Kmat + (size_t)bh * SS * DKK;
  const u16* Vb = Vt   + (size_t)bh * DKK * SS;
  const float LOG2E = 1.4426950408889634f;

  short8v qf0, qf1;
  {
    const u16* qp = Qb + (size_t)(q0 + w * 16 + lr) * DKK + lq * 8;
    qf0 = *(const short8v*)qp;
    qf1 = *(const short8v*)(qp + 32);
  }
  floatx4 o[4] = {{0.f,0.f,0.f,0.f},{0.f,0.f,0.f,0.f},{0.f,0.f,0.f,0.f},{0.f,0.f,0.f,0.f}};
  float m_i[4] = {-1e30f, -1e30f, -1e30f, -1e30f};
  float l_i[4] = {0.f, 0.f, 0.f, 0.f};

  for (int kt = 0; kt < SS / 64; ++kt) {
    const int kbase = kt * 64;
    const u16* kp = Kb + (size_t)(kbase + w * 16 + lr) * DKK + lq * 8;
    const u16* vp = Vb + (size_t)(w * 16 + lr) * SS + kbase + lq * 8;
    load_lds16(kp,      &Ks[(w * 2 + 0) * 512]);
    load_lds16(kp + 32, &Ks[(w * 2 + 1) * 512]);
    load_lds16(vp,      &Vs[(w * 2 + 0) * 512]);
    load_lds16(vp + 32, &Vs[(w * 2 + 1) * 512]);
    __syncthreads();

    // S = Q K^T / sqrt(DK) ; D-layout: row=lq*4+reg (query), col=lane&15 (key in tile t)
    floatx4 sc[4] = {{0.f,0.f,0.f,0.f},{0.f,0.f,0.f,0.f},{0.f,0.f,0.f,0.f},{0.f,0.f,0.f,0.f}};
#pragma unroll
    for (int t = 0; t < 4; ++t) {
      short8v kb0 = *(const short8v*)&Ks[t * 1024 + lane * 8];
      short8v kb1 = *(const short8v*)&Ks[t * 1024 + 512 + lane * 8];
      sc[t] = mfma_bf16(qf0, kb0, sc[t]);
      sc[t] = mfma_bf16(qf1, kb1, sc[t]);
    }
#pragma unroll
    for (int t = 0; t < 4; ++t) sc[t] *= 0.125f;  // 1/sqrt(64)

    float mx[4], alpha[4], rs[4];
#pragma unroll
    for (int r = 0; r < 4; ++r)
      mx[r] = fmaxf(fmaxf(sc[0][r], sc[1][r]), fmaxf(sc[2][r], sc[3][r]));
#pragma unroll
    for (int off = 1; off < 16; off <<= 1) {
#pragma unroll
      for (int r = 0; r < 4; ++r) mx[r] = fmaxf(mx[r], __shfl_xor(mx[r], off));
    }
#pragma unroll
    for (int r = 0; r < 4; ++r) {
      float mn = fmaxf(m_i[r], mx[r]);
      alpha[r] = exp2f((m_i[r] - mn) * LOG2E);
      m_i[r] = mn;
    }
#pragma unroll
    for (int t = 0; t < 4; ++t) {
#pragma unroll
      for (int r = 0; r < 4; ++r)
        sc[t][r] = exp2f((sc[t][r] - m_i[r]) * LOG2E);
    }
#pragma unroll
    for (int r = 0; r < 4; ++r)
      rs[r] = (sc[0][r] + sc[1][r]) + (sc[2][r] + sc[3][r]);
#pragma unroll
    for (int off = 1; off < 16; off <<= 1) {
#pragma unroll
      for (int r = 0; r < 4; ++r) rs[r] += __shfl_xor(rs[r], off);
    }
#pragma unroll
    for (int r = 0; r < 4; ++r) l_i[r] = l_i[r] * alpha[r] + rs[r];
#pragma unroll
    for (int t = 0; t < 4; ++t) {
#pragma unroll
      for (int r = 0; r < 4; ++r) o[t][r] *= alpha[r];
    }

    // P: C/D-layout -> A-operand layout via per-wave LDS region
    u16* pw = &Ps[w * 1024];
#pragma unroll
    for (int t = 0; t < 4; ++t) {
      const int kcol = t * 16 + lr;
      const int coff = (kcol >> 3) * 128 + (kcol & 7);
#pragma unroll
      for (int r = 0; r < 4; ++r)
        pw[coff + (lq * 4 + r) * 8] = f2bf(sc[t][r]);
    }
    short8v pa0 = *(const short8v*)&Ps[w * 1024 + lane * 8];
    short8v pa1 = *(const short8v*)&Ps[w * 1024 + 512 + lane * 8];
#pragma unroll
    for (int t = 0; t < 4; ++t) {
      short8v vb0 = *(const short8v*)&Vs[t * 1024 + lane * 8];
      short8v vb1 = *(const short8v*)&Vs[t * 1024 + 512 + lane * 8];
      o[t] = mfma_bf16(pa0, vb0, o[t]);
      o[t] = mfma_bf16(pa1, vb1, o[t]);
    }
    __syncthreads();
  }

  const int b = bh / HH, h = bh % HH;
#pragma unroll
  for (int r = 0; r < 4; ++r) {
    const int s = q0 + w * 16 + lq * 4 + r;
    const float inv = 1.0f / l_i[r];
#pragma unroll
    for (int t = 0; t < 4; ++t) {
      const int dk = t * 16 + lr;
      ctx[((size_t)b * SS + s) * DD + h * DKK + dk] = f2bf(o[t][r] * inv);
    }
  }
}

// ---------------- launch ----------------
extern "C" void kernel_launch(void* const* d_in, const int* in_sizes, int n_in,
                              void* d_out, int out_size, void* d_ws, size_t ws_size,
                              hipStream_t stream) {
  const float* query = (const float*)d_in[0];
  const float* key   = (const float*)d_in[1];
  const float* value = (const float*)d_in[2];
  const float* Wq = (const float*)d_in[3];  const float* bq = (const float*)d_in[4];
  const float* Wk = (const float*)d_in[5];  const float* bk = (const float*)d_in[6];
  const float* Wv = (const float*)d_in[7];  const float* bv = (const float*)d_in[8];
  const float* Wo = (const float*)d_in[9];  const float* bo = (const float*)d_in[10];
  float* out = (float*)d_out;

  char* ws = (char*)d_ws;
  size_t off = 0;
  u16* Wq_b = (u16*)(ws + off); off += (size_t)DD * DD * 2;
  u16* Wk_b = (u16*)(ws + off); off += (size_t)DD * DD * 2;
  u16* Wv_b = (u16*)(ws + off); off += (size_t)DD * DD * 2;
  u16* Wo_b = (u16*)(ws + off); off += (size_t)DD * DD * 2;
  u16* Qb   = (u16*)(ws + off); off += (size_t)MM * DD * 2;  // [B,H,S,DK]
  u16* Kbuf = (u16*)(ws + off); off += (size_t)MM * DD * 2;  // [B,H,S,DK]
  u16* Vtb  = (u16*)(ws + off); off += (size_t)MM * DD * 2;  // [B,H,DK,S]
  u16* ctxb = (u16*)(ws + off); off += (size_t)MM * DD * 2;  // [B,S,D]

  const int wn = DD * DD;
  cvt_bf16<<<wn / (256 * 8), 256, 0, stream>>>(Wq, Wq_b, wn);
  cvt_bf16<<<wn / (256 * 8), 256, 0, stream>>>(Wk, Wk_b, wn);
  cvt_bf16<<<wn / (256 * 8), 256, 0, stream>>>(Wv, Wv_b, wn);
  cvt_bf16<<<wn / (256 * 8), 256, 0, stream>>>(Wo, Wo_b, wn);

  dim3 gg(MM / 64, NN / 64);
  proj_gemm<0><<<gg, 256, 0, stream>>>(query, Wq_b, bq, Qb);
  proj_gemm<0><<<gg, 256, 0, stream>>>(key,   Wk_b, bk, Kbuf);
  proj_gemm<1><<<gg, 256, 0, stream>>>(value, Wv_b, bv, Vtb);

  attn_kernel<<<dim3(SS / 64, BB * HH), 256, 0, stream>>>(Qb, Kbuf, Vtb, ctxb);

  out_gemm<<<gg, 256, 0, stream>>>(ctxb, Wo_b, bo, out);
}

// Round 2
// 441.292 us; speedup vs baseline: 1.6255x; 1.6255x over previous
//
#include <hip/hip_runtime.h>

typedef unsigned short u16;
typedef unsigned int u32;
typedef __attribute__((ext_vector_type(8))) short short8v;
typedef __attribute__((ext_vector_type(4))) float floatx4;

#define BB 4
#define SS 2048
#define DD 1024
#define HH 16
#define DKK 64
#define MM (BB * SS)   // 8192
#define KK DD
#define NN DD
// log2(e)/sqrt(DK): folded into Q projection so scores are ready for exp2
#define QSCALE 0.18033688011112042f

__device__ __forceinline__ u16 f2bf(float f) {
  union { __bf16 h; u16 u; } r; r.h = (__bf16)f; return r.u;
}
__device__ __forceinline__ u32 pack2bf(float a, float b) {
  union { u32 u; __bf16 h[2]; } r;
  r.h[0] = (__bf16)a; r.h[1] = (__bf16)b; return r.u;
}

__device__ __forceinline__ void load_lds16(const void* g, void* l) {
  __builtin_amdgcn_global_load_lds((const __attribute__((address_space(1))) void*)g,
                                   (__attribute__((address_space(3))) void*)l, 16, 0, 0);
}

__device__ __forceinline__ floatx4 mfma_bf16(short8v a, short8v b, floatx4 c) {
  return __builtin_amdgcn_mfma_f32_16x16x32_bf16(a, b, c, 0, 0, 0);
}

// ---------------- fp32 -> bf16 convert ----------------
__global__ __launch_bounds__(256) void cvt_bf16(const float* __restrict__ in,
                                                u16* __restrict__ out, int n) {
  int i = (blockIdx.x * 256 + threadIdx.x) * 8;
  if (i + 8 > n) return;
  float4 a = *(const float4*)(in + i);
  float4 b = *(const float4*)(in + i + 4);
  uint4 o;
  o.x = pack2bf(a.x, a.y); o.y = pack2bf(a.z, a.w);
  o.z = pack2bf(b.x, b.y); o.w = pack2bf(b.z, b.w);
  *(uint4*)(out + i) = o;
}

// ---------------- GEMM-BT: out = A @ W^T + bias, 128x128 tile, BK=32 ----------------
// A bf16 [M,K]; W bf16 [N,K].
// EPI 0: bf16 store [M,N] ; 1: bf16 store * QSCALE (Q) ; 2: bf16 V^T store [B,H,DK,S] ;
// EPI 3: fp32 store [M,N].
// LDS chunk layout (16 rows x 32 k): off(u16) = koct*128 + row*8 + (k&7); chunk=512 u16.
template <int EPI>
__global__ __launch_bounds__(256) void gemm_bt(const u16* __restrict__ A,
                                               const u16* __restrict__ W,
                                               const float* __restrict__ bias,
                                               void* __restrict__ outv) {
  __shared__ __align__(16) u16 As[128 * 32];  // 8 chunks
  __shared__ __align__(16) u16 Bs[128 * 32];
  const int tid = threadIdx.x;
  const int w = tid >> 6, lane = tid & 63;
  const int lr = lane & 15, lq = lane >> 4;
  const int m0 = blockIdx.x * 128, n0 = blockIdx.y * 128;
  const int wr = w >> 1, wc = w & 1;

  floatx4 acc[4][4] = {};

  // wave w stages A chunks {2w,2w+1} (rows m0+32w..+31) and same for B
  const u16* ga0 = A + (size_t)(m0 + 2 * w * 16 + lr) * KK + lq * 8;
  const u16* ga1 = ga0 + 16 * KK;
  const u16* gb0 = W + (size_t)(n0 + 2 * w * 16 + lr) * KK + lq * 8;
  const u16* gb1 = gb0 + 16 * KK;
  u16* la0 = &As[(2 * w) * 512]; u16* la1 = la0 + 512;
  u16* lb0 = &Bs[(2 * w) * 512]; u16* lb1 = lb0 + 512;

  for (int k0 = 0; k0 < KK; k0 += 32) {
    load_lds16(ga0 + k0, la0);
    load_lds16(ga1 + k0, la1);
    load_lds16(gb0 + k0, lb0);
    load_lds16(gb1 + k0, lb1);
    __syncthreads();
    short8v af[4], bf[4];
#pragma unroll
    for (int i = 0; i < 4; ++i) {
      af[i] = *(const short8v*)&As[(wr * 4 + i) * 512 + lane * 8];
      bf[i] = *(const short8v*)&Bs[(wc * 4 + i) * 512 + lane * 8];
    }
#pragma unroll
    for (int i = 0; i < 4; ++i)
#pragma unroll
      for (int j = 0; j < 4; ++j)
        acc[i][j] = mfma_bf16(af[i], bf[j], acc[i][j]);
    __syncthreads();
  }

#pragma unroll
  for (int j = 0; j < 4; ++j) {
    const int col = n0 + wc * 64 + j * 16 + lr;
    const float bv = bias[col];
#pragma unroll
    for (int i = 0; i < 4; ++i) {
#pragma unroll
      for (int r = 0; r < 4; ++r) {
        const int row = m0 + wr * 64 + i * 16 + lq * 4 + r;
        const float v = acc[i][j][r] + bv;
        if (EPI == 0) {
          ((u16*)outv)[(size_t)row * NN + col] = f2bf(v);
        } else if (EPI == 1) {
          ((u16*)outv)[(size_t)row * NN + col] = f2bf(v * QSCALE);
        } else if (EPI == 2) {
          const int b = row >> 11, s = row & (SS - 1);
          const int h = col >> 6, dk = col & 63;
          ((u16*)outv)[(((size_t)(b * HH + h)) * DKK + dk) * SS + s] = f2bf(v);
        } else {
          ((float*)outv)[(size_t)row * NN + col] = v;
        }
      }
    }
  }
}

// ---------------- flash attention, no-max softmax, 128 q/block ----------------
// Q,K bf16 [B,S,D] (Q pre-scaled by QSCALE); Vt bf16 [B,H,DK,S]; ctx bf16 [B,S,D].
// 4 waves x 32 queries (2 strips of 16). K-tiles of 64 keys.
__global__ __launch_bounds__(256) void attn_kernel(const u16* __restrict__ Q,
                                                   const u16* __restrict__ Kmat,
                                                   const u16* __restrict__ Vt,
                                                   u16* __restrict__ ctx) {
  __shared__ __align__(16) u16 Ks[64 * 64];   // (dk-oct)*128 + key*8 per 16-key chunk
  __shared__ __align__(16) u16 Vs[64 * 64];   // (key-oct)*128 + dk*8 per 16-dk chunk
  __shared__ __align__(16) u16 Ps[4 * 1024];  // per-wave P strip (reused for both strips)
  const int tid = threadIdx.x;
  const int w = tid >> 6, lane = tid & 63;
  const int lr = lane & 15, lq = lane >> 4;
  const int bh = blockIdx.y, b = bh >> 4, h = bh & 15;
  const int q0 = blockIdx.x * 128;

  short8v qf[2][2];
  {
    const u16* qp = Q + ((size_t)(b * SS + q0 + w * 32 + lr)) * DD + h * 64 + lq * 8;
    qf[0][0] = *(const short8v*)qp;
    qf[0][1] = *(const short8v*)(qp + 32);
    qf[1][0] = *(const short8v*)(qp + 16 * DD);
    qf[1][1] = *(const short8v*)(qp + 16 * DD + 32);
  }
  floatx4 o[2][4] = {};
  float l_part[2][4] = {};

  const u16* kp = Kmat + ((size_t)(b * SS + w * 16 + lr)) * DD + h * 64 + lq * 8;
  const u16* vp = Vt + (((size_t)(b * HH + h)) * DKK + w * 16 + lr) * SS + lq * 8;
  u16* pw = &Ps[w * 1024];

  for (int kt = 0; kt < SS / 64; ++kt) {
    load_lds16(kp,      &Ks[(2 * w) * 512]);
    load_lds16(kp + 32, &Ks[(2 * w + 1) * 512]);
    load_lds16(vp,      &Vs[(2 * w) * 512]);
    load_lds16(vp + 32, &Vs[(2 * w + 1) * 512]);
    kp += 64 * DD; vp += 64;
    __syncthreads();

    floatx4 sc[2][4] = {};
#pragma unroll
    for (int t = 0; t < 4; ++t) {
      short8v kb0 = *(const short8v*)&Ks[t * 1024 + lane * 8];
      short8v kb1 = *(const short8v*)&Ks[t * 1024 + 512 + lane * 8];
      sc[0][t] = mfma_bf16(qf[0][0], kb0, sc[0][t]);
      sc[0][t] = mfma_bf16(qf[0][1], kb1, sc[0][t]);
      sc[1][t] = mfma_bf16(qf[1][0], kb0, sc[1][t]);
      sc[1][t] = mfma_bf16(qf[1][1], kb1, sc[1][t]);
    }

    short8v pa[2][2];
#pragma unroll
    for (int s = 0; s < 2; ++s) {
#pragma unroll
      for (int t = 0; t < 4; ++t) {
#pragma unroll
        for (int r = 0; r < 4; ++r) {
          const float e = __builtin_amdgcn_exp2f(sc[s][t][r]);
          sc[s][t][r] = e;
          l_part[s][r] += e;
        }
      }
#pragma unroll
      for (int t = 0; t < 4; ++t) {
        const int coff = (2 * t + (lr >> 3)) * 128 + (lr & 7);
#pragma unroll
        for (int r = 0; r < 4; r += 2) {
          const u32 pr = pack2bf(sc[s][t][r], sc[s][t][r + 1]);
          pw[coff + (lq * 4 + r) * 8]     = (u16)pr;
          pw[coff + (lq * 4 + r + 1) * 8] = (u16)(pr >> 16);
        }
      }
      pa[s][0] = *(const short8v*)&Ps[w * 1024 + lane * 8];
      pa[s][1] = *(const short8v*)&Ps[w * 1024 + 512 + lane * 8];
    }

#pragma unroll
    for (int t = 0; t < 4; ++t) {
      short8v vb0 = *(const short8v*)&Vs[t * 1024 + lane * 8];
      short8v vb1 = *(const short8v*)&Vs[t * 1024 + 512 + lane * 8];
      o[0][t] = mfma_bf16(pa[0][0], vb0, o[0][t]);
      o[0][t] = mfma_bf16(pa[0][1], vb1, o[0][t]);
      o[1][t] = mfma_bf16(pa[1][0], vb0, o[1][t]);
      o[1][t] = mfma_bf16(pa[1][1], vb1, o[1][t]);
    }
    __syncthreads();
  }

  float inv[2][4];
#pragma unroll
  for (int s = 0; s < 2; ++s)
#pragma unroll
    for (int r = 0; r < 4; ++r) {
      float l = l_part[s][r];
      l += __shfl_xor(l, 1); l += __shfl_xor(l, 2);
      l += __shfl_xor(l, 4); l += __shfl_xor(l, 8);
      inv[s][r] = 1.0f / l;
    }

#pragma unroll
  for (int s = 0; s < 2; ++s)
#pragma unroll
    for (int r = 0; r < 4; ++r) {
      const int sq = q0 + w * 32 + s * 16 + lq * 4 + r;
      u16* cp = ctx + ((size_t)(b * SS + sq)) * DD + h * 64;
      const float iv = inv[s][r];
#pragma unroll
      for (int t = 0; t < 4; ++t)
        cp[t * 16 + lr] = f2bf(o[s][t][r] * iv);
    }
}

// ---------------- launch ----------------
extern "C" void kernel_launch(void* const* d_in, const int* in_sizes, int n_in,
                              void* d_out, int out_size, void* d_ws, size_t ws_size,
                              hipStream_t stream) {
  const float* query = (const float*)d_in[0];
  const float* key   = (const float*)d_in[1];
  const float* value = (const float*)d_in[2];
  const float* Wq = (const float*)d_in[3];  const float* bq = (const float*)d_in[4];
  const float* Wk = (const float*)d_in[5];  const float* bk = (const float*)d_in[6];
  const float* Wv = (const float*)d_in[7];  const float* bv = (const float*)d_in[8];
  const float* Wo = (const float*)d_in[9];  const float* bo = (const float*)d_in[10];
  float* out = (float*)d_out;

  char* ws = (char*)d_ws;
  size_t off = 0;
  u16* Wq_b = (u16*)(ws + off); off += (size_t)DD * DD * 2;
  u16* Wk_b = (u16*)(ws + off); off += (size_t)DD * DD * 2;
  u16* Wv_b = (u16*)(ws + off); off += (size_t)DD * DD * 2;
  u16* Wo_b = (u16*)(ws + off); off += (size_t)DD * DD * 2;
  u16* Qb   = (u16*)(ws + off); off += (size_t)MM * DD * 2;  // scaled Q, [B,S,D]
  u16* Kb   = (u16*)(ws + off); off += (size_t)MM * DD * 2;  // [B,S,D]
  u16* Vtb  = (u16*)(ws + off); off += (size_t)MM * DD * 2;  // [B,H,DK,S]
  u16* qc   = (u16*)(ws + off);                              // bf16 query; dead before
  u16* ctxb = qc;                  off += (size_t)MM * DD * 2;  // ctx aliases qc
  // kc/vc scratch lives in d_out (33.5 MB fp32 buffer, overwritten by out_gemm last)
  u16* kc = (u16*)d_out;
  u16* vc = (u16*)d_out + (size_t)MM * DD;

  const int wn = DD * DD, an = MM * DD;
  cvt_bf16<<<wn / 2048, 256, 0, stream>>>(Wq, Wq_b, wn);
  cvt_bf16<<<wn / 2048, 256, 0, stream>>>(Wk, Wk_b, wn);
  cvt_bf16<<<wn / 2048, 256, 0, stream>>>(Wv, Wv_b, wn);
  cvt_bf16<<<wn / 2048, 256, 0, stream>>>(Wo, Wo_b, wn);
  cvt_bf16<<<an / 2048, 256, 0, stream>>>(query, qc, an);
  cvt_bf16<<<an / 2048, 256, 0, stream>>>(key,   kc, an);
  cvt_bf16<<<an / 2048, 256, 0, stream>>>(value, vc, an);

  dim3 gg(MM / 128, NN / 128);
  gemm_bt<1><<<gg, 256, 0, stream>>>(qc, Wq_b, bq, Qb);
  gemm_bt<0><<<gg, 256, 0, stream>>>(kc, Wk_b, bk, Kb);
  gemm_bt<2><<<gg, 256, 0, stream>>>(vc, Wv_b, bv, Vtb);

  attn_kernel<<<dim3(SS / 128, BB * HH), 256, 0, stream>>>(Qb, Kb, Vtb, ctxb);

  gemm_bt<3><<<gg, 256, 0, stream>>>(ctxb, Wo_b, bo, out);
}